// Round 11
// baseline (351.879 us; speedup 1.0000x reference)
//
#include <hip/hip_runtime.h>
#include <hip/hip_cooperative_groups.h>
#include <hip/hip_bf16.h>
#include <math.h>

namespace cg = cooperative_groups;

#define BB 8
#define NN 512
#define DD 256
#define BNT 4096   // B*N

typedef __attribute__((ext_vector_type(8))) short short8;
typedef __attribute__((ext_vector_type(4))) float f32x4;

// Workspace layout (float offsets). ~18 MB.
#define OFF_S0B   0u          // bf16 [4096][256]      s0 row-major (gemmT B)
#define OFF_TT    524288u     // bf16 [8][256][3072]   TT[b][e][r*512+i] = T_r[i][e]+relb_r[e]
#define OFF_WCT   6815744u    // bf16 [256][1536]      WcT[e][r*256+d] = relW[r][d][e]
#define OFF_WBT   7012352u    // bf16 [1024][256]      Wbig^T (c rows, k=d)
#define OFF_BB    7143424u    // fp32 [1024]           h1b|outb
#define OFF_REL   7144448u    // u8   [8][512][512]    relation codes (self=6)

// d_out layout (floats)
#define OUT0_OFF   0u        // output  [8][512][256]
#define INTERP_OFF 1048576u  // interp  [3][4096]
#define SYM_OFF    1060864u  // symbols [8][512][256]

__device__ __forceinline__ float gelu_exact(float x) {
    return 0.5f * x * (1.0f + erff(x * 0.70710678118654752f));
}

__device__ __forceinline__ ushort f2bf(float x) {
    __hip_bfloat16 h = __float2bfloat16(x);
    union { __hip_bfloat16 b; ushort u; } cv;
    cv.b = h;
    return cv.u;
}

// Branch-free classification (reference if/elif priority, applied in reverse).
__device__ __forceinline__ int rel_of(float dx, float dy) {
    int r = (fabsf(dx) < 0.3f && fabsf(dy) < 0.3f) ? 4 : 5;
    r = (dx >  0.5f) ? 3 : r;
    r = (dx < -0.5f) ? 2 : r;
    r = (dy < -0.5f) ? 1 : r;
    r = (dy >  0.5f) ? 0 : r;
    return r;
}

// ====== 64x64-tile MFMA core (4 waves 2x2), double-buffered LDS ===========
// LDS [chunk(k/8)][row] ushort8 (conflict-free b128). Fragments (m89/m91):
// A: m=lane&15,k=quad*8+j; B: n=lane&15; C/D: col=lane&15, row=quad*4+reg.
#define TILE_IDS()                                             \
    const int lane = tid & 63, w = tid >> 6;                   \
    const int wm = w >> 1, wn = w & 1;                         \
    const int quad = lane >> 4, l15 = lane & 15;               \
    const int sm = tid >> 2, sq = tid & 3;

#define MFMA_STEP(Abuf, Bbuf)                                                \
    {                                                                        \
        short8 af[2], bfr[2];                                                \
        _Pragma("unroll")                                                    \
        for (int mt = 0; mt < 2; mt++)                                       \
            af[mt] = *(const short8*)&(Abuf)[(quad * 64 + wm * 32 + mt * 16 + l15) * 8]; \
        _Pragma("unroll")                                                    \
        for (int nt = 0; nt < 2; nt++)                                       \
            bfr[nt] = *(const short8*)&(Bbuf)[(quad * 64 + wn * 32 + nt * 16 + l15) * 8]; \
        _Pragma("unroll")                                                    \
        for (int mt = 0; mt < 2; mt++)                                       \
            _Pragma("unroll")                                                \
            for (int nt = 0; nt < 2; nt++)                                   \
                acc[mt][nt] = __builtin_amdgcn_mfma_f32_16x16x32_bf16(       \
                    af[mt], bfr[nt], acc[mt][nt], 0, 0, 0);                  \
    }

#define ACC_INIT()                                             \
    f32x4 acc[2][2];                                           \
    _Pragma("unroll") for (int mt = 0; mt < 2; mt++)           \
    _Pragma("unroll") for (int nt = 0; nt < 2; nt++)           \
        acc[mt][nt] = (f32x4){0.f, 0.f, 0.f, 0.f};

// Phase-1 job ranges: [0,96) WcT-transpose, [96,160) WbT-transpose,
// [160,224) gather, 224 inits, [225,737) classify.
#define NJOBS1 737

__global__ __launch_bounds__(256, 2) void mega_kernel(
    const int* __restrict__ ids, const float* __restrict__ positions,
    const float* __restrict__ symt, const float* __restrict__ layt,
    const float* __restrict__ relW, const float* __restrict__ relb,
    const float* __restrict__ h1W, const float* __restrict__ h1b,
    const float* __restrict__ h2W, const float* __restrict__ h2b,
    const float* __restrict__ outW, const float* __restrict__ outb,
    float* __restrict__ out, float* __restrict__ ws)
{
    cg::grid_group grid = cg::this_grid();
    __shared__ __align__(16) char shraw[16640];
    const int tid = threadIdx.x;

    ushort* s0b  = (ushort*)(ws + OFF_S0B);
    ushort* TT   = (ushort*)(ws + OFF_TT);
    ushort* WcT  = (ushort*)(ws + OFF_WCT);
    ushort* WbT  = (ushort*)(ws + OFF_WBT);
    float*  bbig = ws + OFF_BB;
    unsigned char* rel = (unsigned char*)(ws + OFF_REL);
    float* out0   = out + OUT0_OFF;
    float* outI   = out + INTERP_OFF;
    float* symOut = out + SYM_OFF;

    // ============================ PHASE 1: front ==========================
    for (int job = blockIdx.x; job < NJOBS1; job += gridDim.x) {
        __syncthreads();
        if (job < 96) {
            // WcT[e][rd] = relW-as-[1536 rd][256 e], coalesced via LDS tile
            float (*tr)[65] = (float(*)[65])shraw;
            int ty = job >> 2, tx = job & 3;
            int rd0 = ty * 64, e0 = tx * 64;
            int x = tid & 63, g = tid >> 6;
#pragma unroll
            for (int k = 0; k < 16; k++) {
                int il = g * 16 + k;
                tr[il][x] = relW[(size_t)(rd0 + il) * DD + e0 + x];
            }
            __syncthreads();
#pragma unroll
            for (int k = 0; k < 16; k++) {
                int el = g * 16 + k;
                WcT[(size_t)(e0 + el) * 1536 + rd0 + x] = f2bf(tr[x][el]);
            }
        } else if (job < 160) {
            // WbT[c][d] = W2[256 d][1024 c] transpose (h1W heads | outW)
            float (*tr)[65] = (float(*)[65])shraw;
            int jt = job - 96;
            int dt = jt >> 4, ct = jt & 15;
            int d0 = dt * 64, c0 = ct * 64;
            int x = tid & 63, g = tid >> 6;
#pragma unroll
            for (int k = 0; k < 16; k++) {
                int dl = g * 16 + k;
                int c = c0 + x;
                float v;
                if (c < 768) v = h1W[(size_t)((c >> 8) * DD + d0 + dl) * DD + (c & 255)];
                else         v = outW[(size_t)(d0 + dl) * DD + (c - 768)];
                tr[dl][x] = v;
            }
            __syncthreads();
#pragma unroll
            for (int k = 0; k < 16; k++) {
                int cl = g * 16 + k;
                WbT[(size_t)(c0 + cl) * DD + d0 + x] = f2bf(tr[x][cl]);
            }
        } else if (job < 224) {
            // gather 64 rows: symOut = s0 (fp32) and s0b (bf16)
            int* idsL = (int*)shraw;
            int n0 = (job - 160) * 64;
            if (tid < 64) idsL[tid] = ids[n0 + tid];
            __syncthreads();
#pragma unroll 4
            for (int k = 0; k < 64; k++) {
                int row = n0 + k;
                int id = idsL[k];
                float v = symt[(size_t)id * DD + tid] + layt[(size_t)id * DD + tid];
                symOut[(size_t)row * DD + tid] = v;
                s0b[(size_t)row * DD + tid] = f2bf(v);
            }
        } else if (job == 224) {
            // inits: outI (h2b broadcast) + bbig
            for (int idx = tid; idx < 3 * BNT + 1024; idx += 256) {
                if (idx < 3 * BNT) outI[idx] = h2b[idx >> 12];
                else {
                    int bbi = idx - 3 * BNT;
                    bbig[bbi] = (bbi < 768) ? h1b[bbi] : outb[bbi - 768];
                }
            }
        } else {
            // classify: 8 j's per job, codes u8 (self=6)
            float* px = (float*)shraw;
            float* py = px + NN;
            int cj = job - 225;
            int b = cj >> 6;
            int j0 = (cj & 63) << 3;
            int jl = tid >> 5, sub = tid & 31;
            for (int i = tid; i < NN; i += 256) {
                float2 p = ((const float2*)positions)[b * NN + i];
                px[i] = p.x; py[i] = p.y;
            }
            __syncthreads();
            int j = j0 + jl;
            float xj = px[j], yj = py[j];
            union { unsigned char u8[16]; uint4 v; } codes;
#pragma unroll
            for (int t = 0; t < 16; t++) {
                int i = sub * 16 + t;
                int r = rel_of(xj - px[i], yj - py[i]);
                r = (i == j) ? 6 : r;
                codes.u8[t] = (unsigned char)r;
            }
            *(uint4*)&rel[((size_t)(b * NN + j)) * NN + sub * 16] = codes.v;
        }
    }
    grid.sync();

    // ============================ PHASE 2: gemmT ==========================
    // TT[b][e][r*512+i] = sum_d relW[r][d][e]*s0[b][i][d] + relb[r][e]
    {
        ushort (*Als)[2048] = (ushort(*)[2048])shraw;
        ushort (*Bls)[2048] = (ushort(*)[2048])(shraw + 8192);
        TILE_IDS();
        for (int job = blockIdx.x; job < 1536; job += gridDim.x) {
            __syncthreads();
            int b = job / 192, rem = job - b * 192;
            int rm = rem >> 3, it = rem & 7;
            int rowM0 = rm * 64, col0 = it * 64;
            int r = rowM0 >> 8, e0 = rowM0 & 255;
            ACC_INIT();
            const ushort* gA = WcT + (size_t)(e0 + sm) * 1536 + r * 256 + sq * 8;
            const ushort* gB = s0b + ((size_t)(b * NN) + col0 + sm) * DD + sq * 8;
            const int lo = (sq * 64 + sm) * 8;
            *(uint4*)&Als[0][lo] = *(const uint4*)gA;
            *(uint4*)&Bls[0][lo] = *(const uint4*)gB;
#pragma unroll
            for (int i = 0; i < 8; i++) {
                __syncthreads();
                uint4 av2, bv2;
                if (i < 7) {
                    av2 = *(const uint4*)(gA + (i + 1) * 32);
                    bv2 = *(const uint4*)(gB + (i + 1) * 32);
                }
                MFMA_STEP(Als[i & 1], Bls[i & 1]);
                if (i < 7) {
                    *(uint4*)&Als[(i + 1) & 1][lo] = av2;
                    *(uint4*)&Bls[(i + 1) & 1][lo] = bv2;
                }
            }
#pragma unroll
            for (int mt = 0; mt < 2; mt++)
#pragma unroll
                for (int nt = 0; nt < 2; nt++)
#pragma unroll
                    for (int v = 0; v < 4; v++) {
                        int e = e0 + wm * 32 + mt * 16 + quad * 4 + v;
                        int i = col0 + wn * 32 + nt * 16 + l15;
                        TT[((size_t)(b * DD) + e) * 3072 + r * 512 + i] =
                            f2bf(acc[mt][nt][v] + relb[r * DD + e]);
                    }
        }
    }
    grid.sync();

    // ============================ PHASE 3: agg ============================
    // symOut[b*512+j][e] += sum_{r,i} 1[rel(i,j)=r] * TT[b][e][r*512+i]
    {
        ushort (*Als)[2048] = (ushort(*)[2048])shraw;
        ushort (*Bls)[2048] = (ushort(*)[2048])(shraw + 8192);
        TILE_IDS();
        for (int job = blockIdx.x; job < 768; job += gridDim.x) {
            __syncthreads();
            int z = job >> 5, rem = job & 31;
            int jt = rem >> 2, et = rem & 3;
            int b = z / 3, rg = z - b * 3;
            int row0 = jt * 64, col0 = et * 64;
            ACC_INIT();
            const unsigned char* gC = rel + ((size_t)(b * NN + row0 + sm)) * NN;
            const ushort* gB = TT + ((size_t)(b * DD) + col0 + sm) * 3072 + rg * 1024 + sq * 8;
            const int lo = (sq * 64 + sm) * 8;
#define AGG_LOADS(i, cw, bv)                                        \
    cw = *(const uint2*)(gC + (((i) * 32 + sq * 8) & 511));         \
    bv = *(const uint4*)(gB + (i) * 32);
#define AGG_STAGE(i, cw, bv, buf)                                   \
    {                                                               \
        int rr_ = 2 * rg + (((i) * 32) >> 9);                       \
        union alignas(16) { ushort u[8]; uint4 v; } am;             \
        _Pragma("unroll")                                           \
        for (int t = 0; t < 8; t++) {                               \
            unsigned int word = (t < 4) ? cw.x : cw.y;              \
            unsigned int code = (word >> (8 * (t & 3))) & 255u;     \
            am.u[t] = (code == (unsigned)rr_) ? 0x3F80 : 0;         \
        }                                                           \
        *(uint4*)&Als[buf][lo] = am.v;                              \
        *(uint4*)&Bls[buf][lo] = bv;                                \
    }
            uint2 cw0; uint4 bv0;
            AGG_LOADS(0, cw0, bv0);
            AGG_STAGE(0, cw0, bv0, 0);
            for (int i = 0; i < 32; i++) {
                __syncthreads();
                uint2 cw2; uint4 bv2;
                if (i < 31) { AGG_LOADS(i + 1, cw2, bv2); }
                MFMA_STEP(Als[i & 1], Bls[i & 1]);
                if (i < 31) { AGG_STAGE(i + 1, cw2, bv2, (i + 1) & 1); }
            }
#undef AGG_LOADS
#undef AGG_STAGE
#pragma unroll
            for (int mt = 0; mt < 2; mt++)
#pragma unroll
                for (int nt = 0; nt < 2; nt++)
#pragma unroll
                    for (int v = 0; v < 4; v++) {
                        int j = row0 + wm * 32 + mt * 16 + quad * 4 + v;
                        int e = col0 + wn * 32 + nt * 16 + l15;
                        atomicAdd(&symOut[((size_t)(b * NN) + j) * DD + e],
                                  acc[mt][nt][v]);
                    }
        }
    }
    grid.sync();

    // ============================ PHASE 4: gemm2 ==========================
    // symOut @ Wbig^T; col tiles <768: gelu + fused interp; else out0.
    {
        ushort (*Als)[2048] = (ushort(*)[2048])shraw;
        ushort (*Bls)[2048] = (ushort(*)[2048])(shraw + 8192);
        TILE_IDS();
        for (int job = blockIdx.x; job < 1024; job += gridDim.x) {
            __syncthreads();
            int rt = job >> 4, ct = job & 15;
            int row0 = rt * 64, col0 = ct * 64;
            ACC_INIT();
            const float*  gA = symOut + (size_t)(row0 + sm) * DD + sq * 8;
            const ushort* gB = WbT    + (size_t)(col0 + sm) * DD + sq * 8;
            const int lo = (sq * 64 + sm) * 8;
#define G2_LOADS(i, a0, a1, bv)                                     \
    a0 = *(const float4*)(gA + (i) * 32);                           \
    a1 = *(const float4*)(gA + (i) * 32 + 4);                       \
    bv = *(const uint4*)(gB + (i) * 32);
#define G2_STAGE(a0, a1, bv, buf)                                   \
    {                                                               \
        union alignas(16) { ushort u[8]; uint4 v; } am;             \
        am.u[0] = f2bf(a0.x); am.u[1] = f2bf(a0.y);                 \
        am.u[2] = f2bf(a0.z); am.u[3] = f2bf(a0.w);                 \
        am.u[4] = f2bf(a1.x); am.u[5] = f2bf(a1.y);                 \
        am.u[6] = f2bf(a1.z); am.u[7] = f2bf(a1.w);                 \
        *(uint4*)&Als[buf][lo] = am.v;                              \
        *(uint4*)&Bls[buf][lo] = bv;                                \
    }
            float4 a0, a1; uint4 bv;
            G2_LOADS(0, a0, a1, bv);
            G2_STAGE(a0, a1, bv, 0);
#pragma unroll
            for (int i = 0; i < 8; i++) {
                __syncthreads();
                float4 a0n, a1n; uint4 bvn;
                if (i < 7) { G2_LOADS(i + 1, a0n, a1n, bvn); }
                MFMA_STEP(Als[i & 1], Bls[i & 1]);
                if (i < 7) { G2_STAGE(a0n, a1n, bvn, (i + 1) & 1); }
            }
#undef G2_LOADS
#undef G2_STAGE
            if (col0 >= 768) {
#pragma unroll
                for (int nt = 0; nt < 2; nt++) {
                    int c = col0 + wn * 32 + nt * 16 + l15;
                    float bb = bbig[c];
#pragma unroll
                    for (int mt = 0; mt < 2; mt++)
#pragma unroll
                        for (int v = 0; v < 4; v++) {
                            int row = row0 + wm * 32 + mt * 16 + quad * 4 + v;
                            out0[(size_t)row * DD + (c - 768)] = acc[mt][nt][v] + bb;
                        }
                }
            } else {
                int head = col0 >> 8;
                float part[2][4];
#pragma unroll
                for (int mt = 0; mt < 2; mt++)
#pragma unroll
                    for (int v = 0; v < 4; v++) part[mt][v] = 0.f;
#pragma unroll
                for (int nt = 0; nt < 2; nt++) {
                    int c = col0 + wn * 32 + nt * 16 + l15;
                    float bb = bbig[c];
                    float w2 = h2W[c];
#pragma unroll
                    for (int mt = 0; mt < 2; mt++)
#pragma unroll
                        for (int v = 0; v < 4; v++)
                            part[mt][v] += gelu_exact(acc[mt][nt][v] + bb) * w2;
                }
#pragma unroll
                for (int mt = 0; mt < 2; mt++)
#pragma unroll
                    for (int v = 0; v < 4; v++) {
                        float p = part[mt][v];
                        p += __shfl_xor(p, 1); p += __shfl_xor(p, 2);
                        p += __shfl_xor(p, 4); p += __shfl_xor(p, 8);
                        if (l15 == 0) {
                            int row = row0 + wm * 32 + mt * 16 + quad * 4 + v;
                            atomicAdd(&outI[head * BNT + row], p);
                        }
                    }
            }
        }
    }
}

// ---------------------------------------------------------------- launch --
extern "C" void kernel_launch(void* const* d_in, const int* in_sizes, int n_in,
                              void* d_out, int out_size, void* d_ws, size_t ws_size,
                              hipStream_t stream)
{
    const int*   ids  = (const int*)d_in[0];
    const float* pos  = (const float*)d_in[1];
    const float* symt = (const float*)d_in[2];
    const float* layt = (const float*)d_in[3];
    const float* relW = (const float*)d_in[4];
    const float* relb = (const float*)d_in[5];
    const float* h1W  = (const float*)d_in[6];
    const float* h1b  = (const float*)d_in[7];
    const float* h2W  = (const float*)d_in[8];
    const float* h2b  = (const float*)d_in[9];
    const float* outW = (const float*)d_in[10];
    const float* outb = (const float*)d_in[11];
    float* out = (float*)d_out;
    float* ws  = (float*)d_ws;

    void* args[] = { (void*)&ids, (void*)&pos, (void*)&symt, (void*)&layt,
                     (void*)&relW, (void*)&relb, (void*)&h1W, (void*)&h1b,
                     (void*)&h2W, (void*)&h2b, (void*)&outW, (void*)&outb,
                     (void*)&out, (void*)&ws };
    hipLaunchCooperativeKernel((void*)mega_kernel, dim3(512), dim3(256),
                               args, 0, stream);
}

// Round 12
// 144.544 us; speedup vs baseline: 2.4344x; 2.4344x over previous
//
#include <hip/hip_runtime.h>
#include <hip/hip_bf16.h>
#include <math.h>

#define BB 8
#define NN 512
#define DD 256
#define BNT 4096   // B*N

typedef __attribute__((ext_vector_type(8))) short short8;
typedef __attribute__((ext_vector_type(4))) float f32x4;

// Workspace layout (float offsets). ~18 MB.
#define OFF_S0B   0u          // bf16 [4096][256]      s0 row-major (gemmT B)
#define OFF_TT    524288u     // bf16 [8][256][3072]   TT[b][e][r*512+i] = T_r[i][e]+relb_r[e]
#define OFF_WCT   6815744u    // bf16 [256][1536]      WcT[e][r*256+d] = relW[r][d][e]
#define OFF_WBT   7012352u    // bf16 [1024][256]      Wbig^T (c rows, k=d)
#define OFF_BB    7143424u    // fp32 [1024]           h1b|outb
#define OFF_REL   7144448u    // u8   [8][512][512]    relation codes (self=6)

// d_out layout (floats)
#define OUT0_OFF   0u        // output  [8][512][256]
#define INTERP_OFF 1048576u  // interp  [3][4096]
#define SYM_OFF    1060864u  // symbols [8][512][256]

__device__ __forceinline__ float gelu_exact(float x) {
    return 0.5f * x * (1.0f + erff(x * 0.70710678118654752f));
}

__device__ __forceinline__ ushort f2bf(float x) {
    __hip_bfloat16 h = __float2bfloat16(x);
    union { __hip_bfloat16 b; ushort u; } cv;
    cv.b = h;
    return cv.u;
}

// Branch-free classification (reference if/elif priority, applied in reverse).
__device__ __forceinline__ int rel_of(float dx, float dy) {
    int r = (fabsf(dx) < 0.3f && fabsf(dy) < 0.3f) ? 4 : 5;
    r = (dx >  0.5f) ? 3 : r;
    r = (dx < -0.5f) ? 2 : r;
    r = (dy < -0.5f) ? 1 : r;
    r = (dy >  0.5f) ? 0 : r;
    return r;
}

// ====== 64x64-tile MFMA core (4 waves 2x2), double-buffered LDS ===========
// LDS [chunk(k/8)][row] ushort8 (conflict-free b128 reads). Fragments
// (m89/m91 verified): A: m=lane&15,k=quad*8+j; B: n=lane&15;
// C/D: col=lane&15, row=quad*4+reg.
#define TILE_IDS()                                             \
    const int lane = tid & 63, w = tid >> 6;                   \
    const int wm = w >> 1, wn = w & 1;                         \
    const int quad = lane >> 4, l15 = lane & 15;               \
    const int sm = tid >> 2, sq = tid & 3;

#define MFMA_STEP(Abuf, Bbuf)                                                \
    {                                                                        \
        short8 af[2], bfr[2];                                                \
        _Pragma("unroll")                                                    \
        for (int mt = 0; mt < 2; mt++)                                       \
            af[mt] = *(const short8*)&(Abuf)[(quad * 64 + wm * 32 + mt * 16 + l15) * 8]; \
        _Pragma("unroll")                                                    \
        for (int nt = 0; nt < 2; nt++)                                       \
            bfr[nt] = *(const short8*)&(Bbuf)[(quad * 64 + wn * 32 + nt * 16 + l15) * 8]; \
        _Pragma("unroll")                                                    \
        for (int mt = 0; mt < 2; mt++)                                       \
            _Pragma("unroll")                                                \
            for (int nt = 0; nt < 2; nt++)                                   \
                acc[mt][nt] = __builtin_amdgcn_mfma_f32_16x16x32_bf16(       \
                    af[mt], bfr[nt], acc[mt][nt], 0, 0, 0);                  \
    }

#define ACC_INIT()                                             \
    f32x4 acc[2][2];                                           \
    _Pragma("unroll") for (int mt = 0; mt < 2; mt++)           \
    _Pragma("unroll") for (int nt = 0; nt < 2; nt++)           \
        acc[mt][nt] = (f32x4){0.f, 0.f, 0.f, 0.f};

// ---------------------------------------------------------------- front ---
// Fused prep (blocks 0..1535) + gather (1536..5631) + classify (5632..6143).
__global__ __launch_bounds__(256) void front_kernel(
    const int* __restrict__ ids, const float* __restrict__ positions,
    const float* __restrict__ symt, const float* __restrict__ layt,
    const float* __restrict__ relW, const float* __restrict__ h1W,
    const float* __restrict__ outW, const float* __restrict__ h1b,
    const float* __restrict__ outb, const float* __restrict__ h2b,
    ushort* __restrict__ WcT, ushort* __restrict__ WbT,
    float* __restrict__ bbig, float* __restrict__ outI,
    float* __restrict__ symOut, ushort* __restrict__ s0b,
    unsigned char* __restrict__ rel)
{
    __shared__ float px[NN], py[NN];
    int blk = blockIdx.x, tid = threadIdx.x;
    if (blk < 1536) {
        int idx = blk * 256 + tid;               // 393216
        {
            int e = idx / 1536, k = idx - e * 1536;
            int r = k >> 8, d = k & 255;
            WcT[idx] = f2bf(relW[(r * DD + d) * DD + e]);
        }
        if (idx < 262144) {
            int c = idx >> 8, d = idx & 255;
            float v;
            if (c < 768) { int r = c >> 8, e = c & 255; v = h1W[(r * DD + d) * DD + e]; }
            else         { v = outW[d * DD + (c - 768)]; }
            WbT[idx] = f2bf(v);
        }
        if (idx < 3 * BNT) outI[idx] = h2b[idx >> 12];
        if (idx < 1024) bbig[idx] = (idx < 768) ? h1b[idx] : outb[idx - 768];
    } else if (blk < 5632) {
        int row = blk - 1536;                    // [0,4096)
        int id = ids[row];
        float v = symt[id * DD + tid] + layt[id * DD + tid];
        symOut[(size_t)row * DD + tid] = v;
        s0b[(size_t)row * DD + tid] = f2bf(v);
    } else {
        int blk2 = blk - 5632;                   // [0,512)
        int b = blk2 >> 6;
        int j0 = (blk2 & 63) << 3;
        int jl = tid >> 5, sub = tid & 31;       // 8 j's x 32 workers x 16 i's
        for (int i = tid; i < NN; i += 256) {
            float2 p = ((const float2*)positions)[b * NN + i];
            px[i] = p.x; py[i] = p.y;
        }
        __syncthreads();
        int j = j0 + jl;
        float xj = px[j], yj = py[j];
        union { unsigned char u8[16]; uint4 v; } codes;
#pragma unroll
        for (int t = 0; t < 16; t++) {
            int i = sub * 16 + t;
            int r = rel_of(xj - px[i], yj - py[i]);
            r = (i == j) ? 6 : r;
            codes.u8[t] = (unsigned char)r;
        }
        *(uint4*)&rel[((size_t)(b * NN + j)) * NN + sub * 16] = codes.v;
    }
}

// ----------------------------------------------------------------- gemmT --
// TT[b][e][r*512+i] = sum_d relW[r][d][e]*s0[b][i][d] + relb[r][e]
// Double-buffered; grid (8 it, 24 rm, 8 b) = 1536 blocks.
__global__ __launch_bounds__(256) void gemmT_kernel(
    const ushort* __restrict__ WcT, const ushort* __restrict__ s0b,
    const float* __restrict__ relb, ushort* __restrict__ TT)
{
    __shared__ ushort Als[2][2048], Bls[2][2048];
    int tid = threadIdx.x;
    int b = blockIdx.z;
    int rowM0 = blockIdx.y * 64;           // in [0,1536): r*256+e
    int col0 = blockIdx.x * 64;            // i tile
    int r = rowM0 >> 8, e0 = rowM0 & 255;
    TILE_IDS();
    ACC_INIT();
    const ushort* gA = WcT + (size_t)(e0 + sm) * 1536 + r * 256 + sq * 8;
    const ushort* gB = s0b + ((size_t)(b * NN) + col0 + sm) * DD + sq * 8;
    const int lo = (sq * 64 + sm) * 8;

    *(uint4*)&Als[0][lo] = *(const uint4*)gA;
    *(uint4*)&Bls[0][lo] = *(const uint4*)gB;
#pragma unroll
    for (int i = 0; i < 8; i++) {
        __syncthreads();
        uint4 av2, bv2;
        if (i < 7) {
            av2 = *(const uint4*)(gA + (i + 1) * 32);
            bv2 = *(const uint4*)(gB + (i + 1) * 32);
        }
        MFMA_STEP(Als[i & 1], Bls[i & 1]);
        if (i < 7) {
            *(uint4*)&Als[(i + 1) & 1][lo] = av2;
            *(uint4*)&Bls[(i + 1) & 1][lo] = bv2;
        }
    }
#pragma unroll
    for (int mt = 0; mt < 2; mt++)
#pragma unroll
        for (int nt = 0; nt < 2; nt++)
#pragma unroll
            for (int v = 0; v < 4; v++) {
                int e = e0 + wm * 32 + mt * 16 + quad * 4 + v;
                int i = col0 + wn * 32 + nt * 16 + l15;
                TT[((size_t)(b * DD) + e) * 3072 + r * 512 + i] =
                    f2bf(acc[mt][nt][v] + relb[r * DD + e]);
            }
}

// ------------------------------------------------------------- agg gemm ---
// symOut[b*512+j][e] += sum_{r,i} 1[rel(i,j)=r] * TT[b][e][r*512+i]
// Per-r split-K (6 slices, K=512): grid (4 et, 8 jt, 48 b*r) = 1536 blocks
// (~6/CU for TLP). One-hot A from u8 codes; double-buffered; atomicAdd
// into symOut (= s0 base written by front).
__global__ __launch_bounds__(256) void agg_gemm(
    const unsigned char* __restrict__ rel, const ushort* __restrict__ TT,
    float* __restrict__ symOut)
{
    __shared__ ushort Als[2][2048], Bls[2][2048];
    int tid = threadIdx.x;
    int z = blockIdx.z;
    int b = z / 6, r = z - b * 6;
    int row0 = blockIdx.y * 64, col0 = blockIdx.x * 64;
    TILE_IDS();
    ACC_INIT();
    const unsigned char* gC = rel + ((size_t)(b * NN + row0 + sm)) * NN + sq * 8;
    const ushort* gB = TT + ((size_t)(b * DD) + col0 + sm) * 3072 + r * 512 + sq * 8;
    const int lo = (sq * 64 + sm) * 8;

#define AGG_LOADS(i, cw, bv)                                        \
    cw = *(const uint2*)(gC + (i) * 32);                            \
    bv = *(const uint4*)(gB + (i) * 32);

#define AGG_STAGE(cw, bv, buf)                                      \
    {                                                               \
        union alignas(16) { ushort u[8]; uint4 v; } am;             \
        _Pragma("unroll")                                           \
        for (int t = 0; t < 8; t++) {                               \
            unsigned int word = (t < 4) ? cw.x : cw.y;              \
            unsigned int code = (word >> (8 * (t & 3))) & 255u;     \
            am.u[t] = (code == (unsigned)r) ? 0x3F80 : 0;           \
        }                                                           \
        *(uint4*)&Als[buf][lo] = am.v;                              \
        *(uint4*)&Bls[buf][lo] = bv;                                \
    }

    uint2 cw0; uint4 bv0;
    AGG_LOADS(0, cw0, bv0);
    AGG_STAGE(cw0, bv0, 0);
#pragma unroll
    for (int i = 0; i < 16; i++) {
        __syncthreads();
        uint2 cw2; uint4 bv2;
        if (i < 15) { AGG_LOADS(i + 1, cw2, bv2); }
        MFMA_STEP(Als[i & 1], Bls[i & 1]);
        if (i < 15) { AGG_STAGE(cw2, bv2, (i + 1) & 1); }
    }
#undef AGG_LOADS
#undef AGG_STAGE
#pragma unroll
    for (int mt = 0; mt < 2; mt++)
#pragma unroll
        for (int nt = 0; nt < 2; nt++)
#pragma unroll
            for (int v = 0; v < 4; v++) {
                int j = row0 + wm * 32 + mt * 16 + quad * 4 + v;
                int e = col0 + wn * 32 + nt * 16 + l15;
                atomicAdd(&symOut[((size_t)(b * NN) + j) * DD + e], acc[mt][nt][v]);
            }
}

// ----------------------------------------------------------------- gemm2 --
// symOut(fp32, bf16 at staging) @ Wbig^T. Col tiles <768: gelu + fused
// interp reduce (atomicAdd into outI pre-loaded with h2b). Else: out0.
__global__ __launch_bounds__(256) void gemm2_kernel(
    const float* __restrict__ symOut, const ushort* __restrict__ WbT,
    const float* __restrict__ bbig, const float* __restrict__ h2W,
    float* __restrict__ out0, float* __restrict__ outI)
{
    __shared__ ushort Als[2][2048], Bls[2][2048];
    int tid = threadIdx.x;
    int row0 = blockIdx.y * 64, col0 = blockIdx.x * 64;
    TILE_IDS();
    ACC_INIT();
    const float*  gA = symOut + (size_t)(row0 + sm) * DD + sq * 8;
    const ushort* gB = WbT    + (size_t)(col0 + sm) * DD + sq * 8;
    const int lo = (sq * 64 + sm) * 8;

#define G2_LOADS(i, a0, a1, bv)                                     \
    a0 = *(const float4*)(gA + (i) * 32);                           \
    a1 = *(const float4*)(gA + (i) * 32 + 4);                       \
    bv = *(const uint4*)(gB + (i) * 32);

#define G2_STAGE(a0, a1, bv, buf)                                   \
    {                                                               \
        union alignas(16) { ushort u[8]; uint4 v; } am;             \
        am.u[0] = f2bf(a0.x); am.u[1] = f2bf(a0.y);                 \
        am.u[2] = f2bf(a0.z); am.u[3] = f2bf(a0.w);                 \
        am.u[4] = f2bf(a1.x); am.u[5] = f2bf(a1.y);                 \
        am.u[6] = f2bf(a1.z); am.u[7] = f2bf(a1.w);                 \
        *(uint4*)&Als[buf][lo] = am.v;                              \
        *(uint4*)&Bls[buf][lo] = bv;                                \
    }

    float4 a0, a1; uint4 bv;
    G2_LOADS(0, a0, a1, bv);
    G2_STAGE(a0, a1, bv, 0);
#pragma unroll
    for (int i = 0; i < 8; i++) {
        __syncthreads();
        float4 a0n, a1n; uint4 bvn;
        if (i < 7) { G2_LOADS(i + 1, a0n, a1n, bvn); }
        MFMA_STEP(Als[i & 1], Bls[i & 1]);
        if (i < 7) { G2_STAGE(a0n, a1n, bvn, (i + 1) & 1); }
    }
#undef G2_LOADS
#undef G2_STAGE
    if (col0 >= 768) {
#pragma unroll
        for (int nt = 0; nt < 2; nt++) {
            int c = col0 + wn * 32 + nt * 16 + l15;
            float bb = bbig[c];
#pragma unroll
            for (int mt = 0; mt < 2; mt++)
#pragma unroll
                for (int v = 0; v < 4; v++) {
                    int row = row0 + wm * 32 + mt * 16 + quad * 4 + v;
                    out0[(size_t)row * DD + (c - 768)] = acc[mt][nt][v] + bb;
                }
        }
    } else {
        int head = col0 >> 8;
        float part[2][4];
#pragma unroll
        for (int mt = 0; mt < 2; mt++)
#pragma unroll
            for (int v = 0; v < 4; v++) part[mt][v] = 0.f;
#pragma unroll
        for (int nt = 0; nt < 2; nt++) {
            int c = col0 + wn * 32 + nt * 16 + l15;
            float bb = bbig[c];
            float w2 = h2W[c];
#pragma unroll
            for (int mt = 0; mt < 2; mt++)
#pragma unroll
                for (int v = 0; v < 4; v++)
                    part[mt][v] += gelu_exact(acc[mt][nt][v] + bb) * w2;
        }
#pragma unroll
        for (int mt = 0; mt < 2; mt++)
#pragma unroll
            for (int v = 0; v < 4; v++) {
                float p = part[mt][v];
                p += __shfl_xor(p, 1); p += __shfl_xor(p, 2);
                p += __shfl_xor(p, 4); p += __shfl_xor(p, 8);
                if (l15 == 0) {
                    int row = row0 + wm * 32 + mt * 16 + quad * 4 + v;
                    atomicAdd(&outI[head * BNT + row], p);
                }
            }
    }
}

// ---------------------------------------------------------------- launch --
extern "C" void kernel_launch(void* const* d_in, const int* in_sizes, int n_in,
                              void* d_out, int out_size, void* d_ws, size_t ws_size,
                              hipStream_t stream)
{
    const int*   ids  = (const int*)d_in[0];
    const float* pos  = (const float*)d_in[1];
    const float* symt = (const float*)d_in[2];
    const float* layt = (const float*)d_in[3];
    const float* relW = (const float*)d_in[4];
    const float* relb = (const float*)d_in[5];
    const float* h1W  = (const float*)d_in[6];
    const float* h1b  = (const float*)d_in[7];
    const float* h2W  = (const float*)d_in[8];
    const float* h2b  = (const float*)d_in[9];
    const float* outW = (const float*)d_in[10];
    const float* outb = (const float*)d_in[11];
    float* out = (float*)d_out;
    float* ws  = (float*)d_ws;

    ushort* s0b  = (ushort*)(ws + OFF_S0B);
    ushort* TT   = (ushort*)(ws + OFF_TT);
    ushort* WcT  = (ushort*)(ws + OFF_WCT);
    ushort* WbT  = (ushort*)(ws + OFF_WBT);
    float*  bbig = ws + OFF_BB;
    unsigned char* rel = (unsigned char*)(ws + OFF_REL);

    front_kernel<<<6144, 256, 0, stream>>>(ids, pos, symt, layt, relW, h1W, outW,
                                           h1b, outb, h2b, WcT, WbT, bbig,
                                           out + INTERP_OFF, out + SYM_OFF, s0b, rel);
    gemmT_kernel<<<dim3(8, 24, 8), 256, 0, stream>>>(WcT, s0b, relb, TT);
    agg_gemm<<<dim3(4, 8, 48), 256, 0, stream>>>(rel, TT, out + SYM_OFF);
    gemm2_kernel<<<dim3(16, 64), 256, 0, stream>>>(out + SYM_OFF, WbT,
                                                   bbig, h2W,
                                                   out + OUT0_OFF, out + INTERP_OFF);
}